// Round 7
// baseline (31.671 us; speedup 1.0000x reference)
//
#include <hip/hip_runtime.h>
#include <hip/hip_bf16.h>

#define BATCH   16384
#define NTAGS   1024
#define DIM     64
#define HID     128

typedef __attribute__((ext_vector_type(8)))  short bf16x8;
typedef __attribute__((ext_vector_type(4)))  float f32x4;
typedef __attribute__((ext_vector_type(16))) float f32x16;

__device__ __forceinline__ unsigned short f2bf(float v) {
    unsigned u = __builtin_bit_cast(unsigned, v);
    return (unsigned short)((u + 0x7FFFu + ((u >> 16) & 1u)) >> 16);   // RNE
}
__device__ __forceinline__ float bf2f(unsigned short u) {
    return __builtin_bit_cast(float, ((unsigned)u) << 16);
}

// ---------------------------------------------------------------------------
// prep_pack32: coalesced-read repack.
//  Sp32 (32x32x16 B-frag layout): elem ((ks*2+nf)*64 + lane)*8 + j
//     holds S[ks*16 + (lane>>5)*8 + j][nf*32 + (lane&31)]      (65536 elems)
//  Wp (16x16x32 B-frag layout, tail): elem ((kt*8+ct)*64 + l)*8 + j
//     holds Wfc[kt*32 + (l>>4)*8 + j][ct*16 + (l&15)]          (24576 elems)
// ---------------------------------------------------------------------------
__global__ __launch_bounds__(256) void prep_pack32(const float* __restrict__ S,
                                                   const float* __restrict__ Wfc,
                                                   unsigned short* __restrict__ Sp32,
                                                   unsigned short* __restrict__ Wp)
{
    int tid = blockIdx.x * 256 + threadIdx.x;   // 0..90111
    if (tid < 65536) {
        int k = tid >> 6, d = tid & 63;
        float v = S[tid];                        // coalesced
        int ks = k >> 4, j = k & 7, kh = (k >> 3) & 1;
        int nf = d >> 5, lane = (d & 31) + 32 * kh;
        Sp32[((size_t)(ks * 2 + nf) * 64 + lane) * 8 + j] = f2bf(v);
    } else if (tid < 65536 + 24576) {
        int t2 = tid - 65536;
        int k = t2 >> 7, col = t2 & 127;
        float v = Wfc[t2];                       // coalesced
        int kt = k >> 5, j = k & 7, l = ((k >> 3) & 3) * 16 + (col & 15), ct = col >> 4;
        Wp[((size_t)(kt * 8 + ct) * 64 + l) * 8 + j] = f2bf(v);
    }
}

// ---------------------------------------------------------------------------
// gemm32: barrier-free, LDS-free. 2048 independent waves (512 blocks x 4).
// Wave gw: mt = gw>>2 (32-row M-tile), ksp = gw&3 (K-quarter of 256).
//   musum_p[ksp][row][d] (bf16) = sum_{k in quarter} T[row][k] * S[k][d]
//   cntp[row][ksp] (f32)        = sum_{k in quarter} T[row][k]   (exact)
// A-frag (32x32x16): row = lane&31, k = (lane>>5)*8 + j
// C layout:          col = lane&31, row = (reg&3) + 8*(reg>>2) + 4*(lane>>5)
// ---------------------------------------------------------------------------
__global__ __launch_bounds__(256) void gemm32(const int* __restrict__ T,
                                              const unsigned short* __restrict__ Sp32,
                                              unsigned short* __restrict__ musum_p,
                                              float* __restrict__ cntp)
{
    const int lane = threadIdx.x & 63;
    const int wid  = threadIdx.x >> 6;
    const int gw   = blockIdx.x * 4 + wid;   // 0..2047
    const int mt   = gw >> 2;                // 0..511
    const int ksp  = gw & 3;
    const int r32  = lane & 31;
    const int kh   = lane >> 5;              // 0/1

    const int* tp = T + (size_t)(mt * 32 + r32) * 1024 + ksp * 256 + kh * 8;
    const unsigned short* spb = Sp32 + (size_t)(ksp * 16) * 1024 + lane * 8;

    f32x16 acc0{}, acc1{};
    int c = 0;
#pragma unroll
    for (int st = 0; st < 16; ++st) {
        int4 t0 = *(const int4*)(tp + st * 16);
        int4 t1 = *(const int4*)(tp + st * 16 + 4);
        c += t0.x + t0.y + t0.z + t0.w + t1.x + t1.y + t1.z + t1.w;   // exact 0/1
        bf16x8 af;
        af[0] = (short)((-t0.x) & 0x3F80);
        af[1] = (short)((-t0.y) & 0x3F80);
        af[2] = (short)((-t0.z) & 0x3F80);
        af[3] = (short)((-t0.w) & 0x3F80);
        af[4] = (short)((-t1.x) & 0x3F80);
        af[5] = (short)((-t1.y) & 0x3F80);
        af[6] = (short)((-t1.z) & 0x3F80);
        af[7] = (short)((-t1.w) & 0x3F80);

        const unsigned short* s2 = spb + st * 1024;
        bf16x8 b0 = *(const bf16x8*)(s2);
        bf16x8 b1 = *(const bf16x8*)(s2 + 512);

        acc0 = __builtin_amdgcn_mfma_f32_32x32x16_bf16(af, b0, acc0, 0, 0, 0);
        acc1 = __builtin_amdgcn_mfma_f32_32x32x16_bf16(af, b1, acc1, 0, 0, 0);
    }

    c += __shfl_xor(c, 32);
    if (lane < 32) cntp[(size_t)(mt * 32 + lane) * 4 + ksp] = (float)c;

    unsigned short* mo = musum_p + (size_t)ksp * BATCH * 64;
#pragma unroll
    for (int reg = 0; reg < 16; ++reg) {
        int rr = (reg & 3) + 8 * (reg >> 2) + 4 * kh;
        size_t base = (size_t)(mt * 32 + rr) * 64 + r32;
        mo[base]      = f2bf(acc0[reg]);
        mo[base + 32] = f2bf(acc1[reg]);
    }
}

// ---------------------------------------------------------------------------
// tail: per block of 16 rows:
//  phase A: mu = (sum_p musum_p)/cnt; q gather; a = df@Wdiff+b; z (bf16, LDS);
//           p12/p13/p23 shuffle-reduced.
//  phase B: e = relu(z@Wfc[0:192] + p*Wfc[192:195] + bfc) via MFMA;
//           p = sigmoid(e@Wout + bout)
// ---------------------------------------------------------------------------
__global__ __launch_bounds__(256) void tail_kernel(
    const int* __restrict__ questions, const float* __restrict__ dfeat,
    const float* __restrict__ Qemb,
    const float* __restrict__ Wdiff, const float* __restrict__ bdiff,
    const float* __restrict__ Wfc, const float* __restrict__ bfc,
    const float* __restrict__ Wout, const float* __restrict__ bout,
    const unsigned short* __restrict__ musum_p, const float* __restrict__ cntp,
    const unsigned short* __restrict__ Wp,
    float* __restrict__ out_e, float* __restrict__ out_p)
{
    __shared__ alignas(16) unsigned short zb[16][200];    // bf16 z rows (192 used)
    __shared__ float scal[16][3];                          // p12,p13,p23
    __shared__ float pacc[16][4];

    const int tid  = threadIdx.x;
    const int lane = tid & 63;
    const int wid  = tid >> 6;
    const int g    = lane >> 4;
    const int rl   = lane & 15;
    const int rb   = blockIdx.x * 16;

    // ---- phase A ------------------------------------------------------------
    {
        int r = tid >> 4, c16 = tid & 15, d0 = c16 * 4;
        int row = rb + r;

        float4 cp = *(const float4*)&cntp[(size_t)row * 4];
        float inv = 1.f / (cp.x + cp.y + cp.z + cp.w);

        float m0 = 0.f, m1 = 0.f, m2 = 0.f, m3 = 0.f;
#pragma unroll
        for (int p = 0; p < 4; ++p) {
            ushort4 mv = *(const ushort4*)&musum_p[((size_t)p * BATCH + row) * 64 + d0];
            m0 += bf2f(mv.x); m1 += bf2f(mv.y); m2 += bf2f(mv.z); m3 += bf2f(mv.w);
        }
        float mu[4] = {m0 * inv, m1 * inv, m2 * inv, m3 * inv};

        int qi = questions[row];
        float4 q4 = *(const float4*)(Qemb + (size_t)qi * 64 + d0);
        float q[4] = {q4.x, q4.y, q4.z, q4.w};

        float f0 = dfeat[row * 3 + 0];
        float f1 = dfeat[row * 3 + 1];
        float f2 = dfeat[row * 3 + 2];
        float aa[4];
#pragma unroll
        for (int d = 0; d < 4; ++d)
            aa[d] = bdiff[d0 + d] + f0 * Wdiff[d0 + d] + f1 * Wdiff[64 + d0 + d]
                  + f2 * Wdiff[128 + d0 + d];

        ushort4 qv, mv, av;
        qv.x = f2bf(q[0]);  qv.y = f2bf(q[1]);  qv.z = f2bf(q[2]);  qv.w = f2bf(q[3]);
        mv.x = f2bf(mu[0]); mv.y = f2bf(mu[1]); mv.z = f2bf(mu[2]); mv.w = f2bf(mu[3]);
        av.x = f2bf(aa[0]); av.y = f2bf(aa[1]); av.z = f2bf(aa[2]); av.w = f2bf(aa[3]);
        *(ushort4*)&zb[r][d0]       = qv;
        *(ushort4*)&zb[r][64 + d0]  = mv;
        *(ushort4*)&zb[r][128 + d0] = av;

        float s12 = 0.f, s13 = 0.f, s23 = 0.f;
#pragma unroll
        for (int d = 0; d < 4; ++d) {
            s12 += q[d] * mu[d];
            s13 += q[d] * aa[d];
            s23 += mu[d] * aa[d];
        }
#pragma unroll
        for (int off = 1; off < 16; off <<= 1) {
            s12 += __shfl_xor(s12, off);
            s13 += __shfl_xor(s13, off);
            s23 += __shfl_xor(s23, off);
        }
        if (c16 == 0) { scal[r][0] = s12; scal[r][1] = s13; scal[r][2] = s23; }
    }
    __syncthreads();

    // ---- phase B: tail GEMM (K=192) + epilogue ------------------------------
    {
        bf16x8 afr[6];
#pragma unroll
        for (int kt = 0; kt < 6; ++kt)
            afr[kt] = *(const bf16x8*)&zb[rl][kt * 32 + g * 8];

        float pr0 = 0.f, pr1 = 0.f, pr2 = 0.f, pr3 = 0.f;
#pragma unroll
        for (int c2 = 0; c2 < 2; ++c2) {
            int ct = wid * 2 + c2;
            f32x4 e{};
            const unsigned short* wp = Wp + (size_t)ct * 512 + lane * 8;
#pragma unroll
            for (int kt = 0; kt < 6; ++kt) {
                bf16x8 bfr = *(const bf16x8*)(wp + (size_t)kt * 4096);
                e = __builtin_amdgcn_mfma_f32_16x16x32_bf16(afr[kt], bfr, e, 0, 0, 0);
            }
            int h = ct * 16 + rl;
            float w192 = Wfc[192 * 128 + h];
            float w193 = Wfc[193 * 128 + h];
            float w194 = Wfc[194 * 128 + h];
            float bb = bfc[h];
            float wo = Wout[h];
#pragma unroll
            for (int r = 0; r < 4; ++r) {
                int row = g * 4 + r;
                float ev = e[r] + bb + scal[row][0] * w192 + scal[row][1] * w193
                         + scal[row][2] * w194;
                ev = ev > 0.f ? ev : 0.f;
                out_e[(size_t)(rb + row) * 128 + h] = ev;
                float pc = ev * wo;
                if (r == 0) pr0 += pc; else if (r == 1) pr1 += pc;
                else if (r == 2) pr2 += pc; else pr3 += pc;
            }
        }
#pragma unroll
        for (int off = 1; off < 16; off <<= 1) {
            pr0 += __shfl_xor(pr0, off);
            pr1 += __shfl_xor(pr1, off);
            pr2 += __shfl_xor(pr2, off);
            pr3 += __shfl_xor(pr3, off);
        }
        if (rl == 0) {
            pacc[g * 4 + 0][wid] = pr0;
            pacc[g * 4 + 1][wid] = pr1;
            pacc[g * 4 + 2][wid] = pr2;
            pacc[g * 4 + 3][wid] = pr3;
        }
    }
    __syncthreads();
    if (tid < 16) {
        float v = pacc[tid][0] + pacc[tid][1] + pacc[tid][2] + pacc[tid][3] + bout[0];
        out_p[rb + tid] = 1.f / (1.f + expf(-v));
    }
}

// ---------------------------------------------------------------------------
extern "C" void kernel_launch(void* const* d_in, const int* in_sizes, int n_in,
                              void* d_out, int out_size, void* d_ws, size_t ws_size,
                              hipStream_t stream)
{
    const int*   questions = (const int*)d_in[0];
    const int*   T         = (const int*)d_in[1];
    const float* dfeat     = (const float*)d_in[2];
    const float* Qemb      = (const float*)d_in[3];
    const float* Semb      = (const float*)d_in[4];
    const float* Wdiff     = (const float*)d_in[5];
    const float* bdiff     = (const float*)d_in[6];
    const float* Wfc       = (const float*)d_in[7];
    const float* bfc       = (const float*)d_in[8];
    const float* Wout      = (const float*)d_in[9];
    const float* bout      = (const float*)d_in[10];

    char* ws = (char*)d_ws;
    unsigned short* Sp32    = (unsigned short*)ws;                        // 128 KiB
    unsigned short* Wp      = (unsigned short*)(ws + 131072);             // 48 KiB
    unsigned short* musum_p = (unsigned short*)(ws + 262144);             // 8 MiB (4 partials, bf16)
    float*          cntp    = (float*)(ws + 262144 + 8388608);            // 256 KiB

    float* out_e = (float*)d_out;
    float* out_p = out_e + (size_t)BATCH * HID;

    hipLaunchKernelGGL(prep_pack32, dim3(352), dim3(256), 0, stream, Semb, Wfc, Sp32, Wp);
    hipLaunchKernelGGL(gemm32, dim3(512), dim3(256), 0, stream, T, Sp32, musum_p, cntp);
    hipLaunchKernelGGL(tail_kernel, dim3(BATCH / 16), dim3(256), 0, stream,
                       questions, dfeat, Qemb, Wdiff, bdiff, Wfc, bfc, Wout, bout,
                       musum_p, cntp, Wp, out_e, out_p);
}

// Round 8
// 29.116 us; speedup vs baseline: 1.0878x; 1.0878x over previous
//
#include <hip/hip_runtime.h>
#include <hip/hip_bf16.h>

#define BATCH   16384
#define NTAGS   1024
#define DIM     64
#define HID     128

typedef __attribute__((ext_vector_type(8))) short bf16x8;
typedef __attribute__((ext_vector_type(4))) float f32x4;

__device__ __forceinline__ unsigned short f2bf(float v) {
    unsigned u = __builtin_bit_cast(unsigned, v);
    return (unsigned short)((u + 0x7FFFu + ((u >> 16) & 1u)) >> 16);   // RNE
}
__device__ __forceinline__ float bf2f(unsigned short u) {
    return __builtin_bit_cast(float, ((unsigned)u) << 16);
}

// ---------------------------------------------------------------------------
// prep (verified in R3): pack S_emb and Wfc[0:192] into bf16 16x16x32
// B-fragment-linear layouts (col = lane&15, k = (lane>>4)*8 + j).
// Spack: [ks(32)][nf(4)][lane(64)][j(8)]   (65536 elems)
// Wp:    [kt(6)][ct(8)][lane(64)][j(8)]    (24576 elems)
// ---------------------------------------------------------------------------
__global__ __launch_bounds__(256) void prep_pack(const float* __restrict__ S,
                                                 const float* __restrict__ Wfc,
                                                 unsigned short* __restrict__ Spack,
                                                 unsigned short* __restrict__ Wp)
{
    int tid = blockIdx.x * 256 + threadIdx.x;   // 0..90111
    if (tid < 65536) {
        int j = tid & 7, l = (tid >> 3) & 63, nf = (tid >> 9) & 3, ks = tid >> 11;
        int k = ks * 32 + (l >> 4) * 8 + j;
        int d = nf * 16 + (l & 15);
        Spack[tid] = f2bf(S[k * 64 + d]);
    } else if (tid < 65536 + 24576) {
        int t2 = tid - 65536;                   // 0..24575
        int j = t2 & 7, l = (t2 >> 3) & 63, ct = (t2 >> 9) & 7, kt = t2 >> 12;
        int k = kt * 32 + (l >> 4) * 8 + j;     // 0..191
        int col = ct * 16 + (l & 15);
        Wp[t2] = f2bf(Wfc[k * 128 + col]);
    }
}

// ---------------------------------------------------------------------------
// mega: ONE wave owns 16 rows end-to-end. ZERO __syncthreads in the kernel.
//   A: full-K (1024) T@S via 16x16x32 bf16 MFMA, counts via int adds+shuffle.
//   B: mu -> wave-private LDS z; q gather; a = df@Wdiff+b; dots; z bf16.
//   C: e = relu(z@Wfc + dots*Wfc[192:195] + bfc) via MFMA (all 8 col-tiles);
//      p = sigmoid(e@Wout + bout).
// Wave-private LDS ordered by lgkmcnt only (same-wave RAW; no barriers).
// 256 blocks x 4 waves = 1024 waves.
// ---------------------------------------------------------------------------
__global__ __launch_bounds__(256) void mega_kernel(
    const int* __restrict__ questions, const int* __restrict__ T,
    const float* __restrict__ dfeat, const float* __restrict__ Qemb,
    const float* __restrict__ Wdiff, const float* __restrict__ bdiff,
    const float* __restrict__ Wfc, const float* __restrict__ bfc,
    const float* __restrict__ Wout, const float* __restrict__ bout,
    const unsigned short* __restrict__ Spack, const unsigned short* __restrict__ Wp,
    float* __restrict__ out_e, float* __restrict__ out_p)
{
    __shared__ alignas(16) unsigned short zb[4][16][200];  // per-wave z (192 used)
    __shared__ float cnt16[4][16];
    __shared__ float scal[4][16][3];

    const int tid  = threadIdx.x;
    const int lane = tid & 63;
    const int wid  = tid >> 6;
    const int g    = lane >> 4;
    const int rl   = lane & 15;
    const int wrow = (blockIdx.x * 4 + wid) * 16;          // this wave's 16 rows

    unsigned short (*z)[200] = zb[wid];
    float* cw = cnt16[wid];
    float (*sc)[3] = scal[wid];

    // ---- phase A: full-K T@S -----------------------------------------------
    f32x4 a0{}, a1{}, a2{}, a3{};
    int c = 0;
    {
        const int* tp = T + (size_t)(wrow + rl) * 1024 + g * 8;
        const unsigned short* sp = Spack + lane * 8;

        int4 t0 = *(const int4*)(tp);
        int4 t1 = *(const int4*)(tp + 4);
#pragma unroll
        for (int st = 0; st < 32; ++st) {
            int4 c0 = t0, c1 = t1;
            if (st < 31) {
                t0 = *(const int4*)(tp + (st + 1) * 32);
                t1 = *(const int4*)(tp + (st + 1) * 32 + 4);
            }
            c += c0.x + c0.y + c0.z + c0.w + c1.x + c1.y + c1.z + c1.w;
            bf16x8 af;
            af[0] = (short)((-c0.x) & 0x3F80);
            af[1] = (short)((-c0.y) & 0x3F80);
            af[2] = (short)((-c0.z) & 0x3F80);
            af[3] = (short)((-c0.w) & 0x3F80);
            af[4] = (short)((-c1.x) & 0x3F80);
            af[5] = (short)((-c1.y) & 0x3F80);
            af[6] = (short)((-c1.z) & 0x3F80);
            af[7] = (short)((-c1.w) & 0x3F80);

            const unsigned short* s2 = sp + st * 2048;
            bf16x8 b0 = *(const bf16x8*)(s2);
            bf16x8 b1 = *(const bf16x8*)(s2 + 512);
            bf16x8 b2 = *(const bf16x8*)(s2 + 1024);
            bf16x8 b3 = *(const bf16x8*)(s2 + 1536);

            a0 = __builtin_amdgcn_mfma_f32_16x16x32_bf16(af, b0, a0, 0, 0, 0);
            a1 = __builtin_amdgcn_mfma_f32_16x16x32_bf16(af, b1, a1, 0, 0, 0);
            a2 = __builtin_amdgcn_mfma_f32_16x16x32_bf16(af, b2, a2, 0, 0, 0);
            a3 = __builtin_amdgcn_mfma_f32_16x16x32_bf16(af, b3, a3, 0, 0, 0);
        }
    }
    // counts: lane holds partial for row rl over its k-slices; reduce over g
    c += __shfl_xor(c, 16);
    c += __shfl_xor(c, 32);
    if (lane < 16) cw[lane] = (float)c;        // lane (g=0, rl) -> cnt[rl]

    // mu -> LDS (bf16). Lane (g,rl) holds musum[row=g*4+r][d=nt*16+rl].
    {
        float inv[4];
#pragma unroll
        for (int r = 0; r < 4; ++r) inv[r] = 1.f / cw[g * 4 + r];
#pragma unroll
        for (int r = 0; r < 4; ++r) {
            int row = g * 4 + r;
            z[row][64 + rl]      = f2bf(a0[r] * inv[r]);
            z[row][64 + 16 + rl] = f2bf(a1[r] * inv[r]);
            z[row][64 + 32 + rl] = f2bf(a2[r] * inv[r]);
            z[row][64 + 48 + rl] = f2bf(a3[r] * inv[r]);
        }
    }

    // ---- phase B: q, a, dots; finish z ------------------------------------
    {
        int r = lane >> 2, q4 = lane & 3, d0 = q4 * 16;   // 4 lanes per row
        int row = wrow + r;
        int qi = questions[row];

        float q[16], aa[16], mu[16];
#pragma unroll
        for (int b = 0; b < 4; ++b) {
            float4 v = *(const float4*)(Qemb + (size_t)qi * 64 + d0 + b * 4);
            q[b * 4 + 0] = v.x; q[b * 4 + 1] = v.y; q[b * 4 + 2] = v.z; q[b * 4 + 3] = v.w;
        }
        float f0 = dfeat[row * 3 + 0];
        float f1 = dfeat[row * 3 + 1];
        float f2 = dfeat[row * 3 + 2];
#pragma unroll
        for (int b = 0; b < 4; ++b) {
            float4 w0 = *(const float4*)(Wdiff + d0 + b * 4);
            float4 w1 = *(const float4*)(Wdiff + 64 + d0 + b * 4);
            float4 w2 = *(const float4*)(Wdiff + 128 + d0 + b * 4);
            float4 bd = *(const float4*)(bdiff + d0 + b * 4);
            aa[b * 4 + 0] = bd.x + f0 * w0.x + f1 * w1.x + f2 * w2.x;
            aa[b * 4 + 1] = bd.y + f0 * w0.y + f1 * w1.y + f2 * w2.y;
            aa[b * 4 + 2] = bd.z + f0 * w0.z + f1 * w1.z + f2 * w2.z;
            aa[b * 4 + 3] = bd.w + f0 * w0.w + f1 * w1.w + f2 * w2.w;
        }
        // mu back from LDS (bf16) — same-wave RAW, lgkmcnt-ordered
#pragma unroll
        for (int b = 0; b < 2; ++b) {
            ushort4 m0 = *(const ushort4*)&z[r][64 + d0 + b * 8];
            ushort4 m1 = *(const ushort4*)&z[r][64 + d0 + b * 8 + 4];
            mu[b * 8 + 0] = bf2f(m0.x); mu[b * 8 + 1] = bf2f(m0.y);
            mu[b * 8 + 2] = bf2f(m0.z); mu[b * 8 + 3] = bf2f(m0.w);
            mu[b * 8 + 4] = bf2f(m1.x); mu[b * 8 + 5] = bf2f(m1.y);
            mu[b * 8 + 6] = bf2f(m1.z); mu[b * 8 + 7] = bf2f(m1.w);
        }
        float s12 = 0.f, s13 = 0.f, s23 = 0.f;
#pragma unroll
        for (int d = 0; d < 16; ++d) {
            s12 += q[d] * mu[d];
            s13 += q[d] * aa[d];
            s23 += mu[d] * aa[d];
        }
        s12 += __shfl_xor(s12, 1); s12 += __shfl_xor(s12, 2);
        s13 += __shfl_xor(s13, 1); s13 += __shfl_xor(s13, 2);
        s23 += __shfl_xor(s23, 1); s23 += __shfl_xor(s23, 2);
        if (q4 == 0) { sc[r][0] = s12; sc[r][1] = s13; sc[r][2] = s23; }

        ushort4 v;
#pragma unroll
        for (int b = 0; b < 4; ++b) {
            v.x = f2bf(q[b * 4 + 0]); v.y = f2bf(q[b * 4 + 1]);
            v.z = f2bf(q[b * 4 + 2]); v.w = f2bf(q[b * 4 + 3]);
            *(ushort4*)&z[r][d0 + b * 4] = v;
        }
#pragma unroll
        for (int b = 0; b < 4; ++b) {
            v.x = f2bf(aa[b * 4 + 0]); v.y = f2bf(aa[b * 4 + 1]);
            v.z = f2bf(aa[b * 4 + 2]); v.w = f2bf(aa[b * 4 + 3]);
            *(ushort4*)&z[r][128 + d0 + b * 4] = v;
        }
    }

    // ---- phase C: tail GEMM (K=192, all 8 col-tiles) + epilogue ------------
    {
        bf16x8 afr[6];
#pragma unroll
        for (int kt = 0; kt < 6; ++kt)
            afr[kt] = *(const bf16x8*)&z[rl][kt * 32 + g * 8];

        float s0 = sc[g * 4 + 0][0], s1 = sc[g * 4 + 0][1], s2 = sc[g * 4 + 0][2];
        float t0_ = sc[g * 4 + 1][0], t1_ = sc[g * 4 + 1][1], t2_ = sc[g * 4 + 1][2];
        float u0 = sc[g * 4 + 2][0], u1 = sc[g * 4 + 2][1], u2 = sc[g * 4 + 2][2];
        float v0 = sc[g * 4 + 3][0], v1 = sc[g * 4 + 3][1], v2 = sc[g * 4 + 3][2];

        float pr0 = 0.f, pr1 = 0.f, pr2 = 0.f, pr3 = 0.f;
#pragma unroll
        for (int ct = 0; ct < 8; ++ct) {
            f32x4 e{};
            const unsigned short* wp = Wp + (size_t)ct * 512 + lane * 8;
#pragma unroll
            for (int kt = 0; kt < 6; ++kt) {
                bf16x8 bfr = *(const bf16x8*)(wp + (size_t)kt * 4096);
                e = __builtin_amdgcn_mfma_f32_16x16x32_bf16(afr[kt], bfr, e, 0, 0, 0);
            }
            int h = ct * 16 + rl;
            float w192 = Wfc[192 * 128 + h];
            float w193 = Wfc[193 * 128 + h];
            float w194 = Wfc[194 * 128 + h];
            float bb = bfc[h];
            float wo = Wout[h];

            float ev;
            ev = e[0] + bb + s0 * w192 + s1 * w193 + s2 * w194;
            ev = ev > 0.f ? ev : 0.f;
            out_e[(size_t)(wrow + g * 4 + 0) * 128 + h] = ev;  pr0 += ev * wo;
            ev = e[1] + bb + t0_ * w192 + t1_ * w193 + t2_ * w194;
            ev = ev > 0.f ? ev : 0.f;
            out_e[(size_t)(wrow + g * 4 + 1) * 128 + h] = ev;  pr1 += ev * wo;
            ev = e[2] + bb + u0 * w192 + u1 * w193 + u2 * w194;
            ev = ev > 0.f ? ev : 0.f;
            out_e[(size_t)(wrow + g * 4 + 2) * 128 + h] = ev;  pr2 += ev * wo;
            ev = e[3] + bb + v0 * w192 + v1 * w193 + v2 * w194;
            ev = ev > 0.f ? ev : 0.f;
            out_e[(size_t)(wrow + g * 4 + 3) * 128 + h] = ev;  pr3 += ev * wo;
        }
#pragma unroll
        for (int off = 1; off < 16; off <<= 1) {
            pr0 += __shfl_xor(pr0, off);
            pr1 += __shfl_xor(pr1, off);
            pr2 += __shfl_xor(pr2, off);
            pr3 += __shfl_xor(pr3, off);
        }
        if (rl == 0) {
            float bo = bout[0];
            out_p[wrow + g * 4 + 0] = 1.f / (1.f + expf(-(pr0 + bo)));
            out_p[wrow + g * 4 + 1] = 1.f / (1.f + expf(-(pr1 + bo)));
            out_p[wrow + g * 4 + 2] = 1.f / (1.f + expf(-(pr2 + bo)));
            out_p[wrow + g * 4 + 3] = 1.f / (1.f + expf(-(pr3 + bo)));
        }
    }
}

// ---------------------------------------------------------------------------
extern "C" void kernel_launch(void* const* d_in, const int* in_sizes, int n_in,
                              void* d_out, int out_size, void* d_ws, size_t ws_size,
                              hipStream_t stream)
{
    const int*   questions = (const int*)d_in[0];
    const int*   T         = (const int*)d_in[1];
    const float* dfeat     = (const float*)d_in[2];
    const float* Qemb      = (const float*)d_in[3];
    const float* Semb      = (const float*)d_in[4];
    const float* Wdiff     = (const float*)d_in[5];
    const float* bdiff     = (const float*)d_in[6];
    const float* Wfc       = (const float*)d_in[7];
    const float* bfc       = (const float*)d_in[8];
    const float* Wout      = (const float*)d_in[9];
    const float* bout      = (const float*)d_in[10];

    char* ws = (char*)d_ws;
    unsigned short* Spack = (unsigned short*)ws;             // 128 KiB
    unsigned short* Wp    = (unsigned short*)(ws + 131072);  // 48 KiB

    float* out_e = (float*)d_out;
    float* out_p = out_e + (size_t)BATCH * HID;

    hipLaunchKernelGGL(prep_pack, dim3(352), dim3(256), 0, stream, Semb, Wfc, Spack, Wp);
    hipLaunchKernelGGL(mega_kernel, dim3(BATCH / 64), dim3(256), 0, stream,
                       questions, T, dfeat, Qemb, Wdiff, bdiff, Wfc, bfc, Wout, bout,
                       Spack, Wp, out_e, out_p);
}